// Round 3
// baseline (1509.925 us; speedup 1.0000x reference)
//
#include <hip/hip_runtime.h>
#include <hip/hip_bf16.h>

#define B_ 8
#define N_ 4096
#define D_ 512
#define BM 32          // q-rows per block
#define BK 64          // m-rows per K-tile
#define NTH 512

typedef __attribute__((ext_vector_type(8))) short bf16x8;
typedef __attribute__((ext_vector_type(4))) float f32x4;
typedef __attribute__((ext_vector_type(4))) short short4v;

__device__ __forceinline__ short f2bs(float x) {
  union { __hip_bfloat16 h; short s; } u;
  u.h = __float2bfloat16(x);
  return u.s;
}

__device__ __forceinline__ void gld16(const void* g, void* l) {
  __builtin_amdgcn_global_load_lds((const __attribute__((address_space(1))) void*)g,
                                   (__attribute__((address_space(3))) void*)l, 16, 0, 0);
}

// ---------------- kernel 1: rn[b*N+n] = 1/||tgt[b,n,:]|| ----------------
__global__ void __launch_bounds__(256) rnorm_kernel(const float* __restrict__ tgt,
                                                    float* __restrict__ rn) {
  int row  = blockIdx.x * 4 + (threadIdx.x >> 6);
  int lane = threadIdx.x & 63;
  const float* p = tgt + (size_t)row * D_ + lane * 8;
  float4 a = *(const float4*)p;
  float4 b = *(const float4*)(p + 4);
  float s = a.x*a.x + a.y*a.y + a.z*a.z + a.w*a.w
          + b.x*b.x + b.y*b.y + b.z*b.z + b.w*b.w;
  #pragma unroll
  for (int m = 32; m >= 1; m >>= 1) s += __shfl_xor(s, m, 64);
  if (lane == 0) rn[row] = rsqrtf(s);
}

// ---------------- kernel 2: prep  Tbf = bf16(tgt*rn) [b][n][d],
//                                  Ttbf = bf16(tgt)^T [b][d][n] ----------------
__global__ void __launch_bounds__(256) prep_kernel(const float* __restrict__ tgt,
                                                   const float* __restrict__ rn,
                                                   ushort* __restrict__ Tbf,
                                                   ushort* __restrict__ Ttbf) {
  __shared__ ushort L[64][66];                 // raw bf16 tile, padded
  const int id = blockIdx.x;                   // 8b x 64nt x 8dt
  const int b = id >> 9, nt = (id >> 3) & 63, dt = id & 7;
  const int n0 = nt * 64, d0 = dt * 64;
  const int t = threadIdx.x;
  const float* Tg  = tgt + ((size_t)b * N_ + n0) * D_ + d0;
  const float* rnb = rn + b * N_ + n0;
  ushort* Tbp = Tbf + ((size_t)b * N_ + n0) * D_ + d0;

  const int r0 = t >> 4, c = (t & 15) * 4;
  #pragma unroll
  for (int p = 0; p < 4; ++p) {
    int r = p * 16 + r0;
    float4 v = *(const float4*)(Tg + (size_t)r * D_ + c);
    float sc = rnb[r];
    short4v nv; nv[0]=f2bs(v.x*sc); nv[1]=f2bs(v.y*sc); nv[2]=f2bs(v.z*sc); nv[3]=f2bs(v.w*sc);
    *(short4v*)(Tbp + (size_t)r * D_ + c) = nv;
    L[r][c+0]=(ushort)f2bs(v.x); L[r][c+1]=(ushort)f2bs(v.y);
    L[r][c+2]=(ushort)f2bs(v.z); L[r][c+3]=(ushort)f2bs(v.w);
  }
  __syncthreads();
  const int dr = t >> 2, nc = (t & 3) * 16;
  bf16x8 o0, o1;
  #pragma unroll
  for (int i = 0; i < 8; ++i) o0[i] = (short)L[nc + i][dr];
  #pragma unroll
  for (int i = 0; i < 8; ++i) o1[i] = (short)L[nc + 8 + i][dr];
  ushort* Vp = Ttbf + ((size_t)b * D_ + d0 + dr) * N_ + n0 + nc;
  *(bf16x8*)Vp = o0;
  *(bf16x8*)(Vp + 8) = o1;
}

// ---------------- kernel 3: fused  out = tanh(Xn Xn^T) * tgt ----------------
// BM=32 q-rows/block, 8 waves. S: 2r x 4c wave grid ([16x16] each, Q in regs).
// PV: wave w owns d-cols [w*64,w*64+64), V B-frags direct from Ttbf (L2).
// 2 barriers/tile; stage(t+1) via global_load_lds overlapped with PV(t).
__global__ void __launch_bounds__(NTH, 4) fused_kernel(const ushort* __restrict__ Tbf,
                                                       const ushort* __restrict__ Ttbf,
                                                       float* __restrict__ out) {
  __shared__ ushort KV[BK * D_];         // 64 KB, row 1024B, 16B-slot swizzled
  __shared__ ushort Pl[2][BM * BK];      // 2 x 4 KB, swizzled

  const int id = blockIdx.x;             // 1024 blocks
  const int b  = id & 7;                 // batch -> XCD (consecutive ids round-robin XCDs)
  const int q0 = (id >> 3) * BM;

  const int tid  = threadIdx.x;
  const int lane = tid & 63;
  const int w    = tid >> 6;

  const ushort* Tb = Tbf  + (size_t)b * N_ * D_;   // normalized bf16 [n][d]
  const ushort* Vt = Ttbf + (size_t)b * D_ * N_;   // raw bf16 [d][n]

  // S mapping: wave -> rows [rq0,rq0+16), cols [kc0,kc0+16)
  const int rq0 = (w >> 2) * 16;
  const int kc0 = (w & 3) * 16;

  // Q fragments (normalized) in registers: 16 rows x 512 d = 64 VGPR
  bf16x8 qf[16];
  {
    const ushort* qp = Tb + (size_t)(q0 + rq0 + (lane & 15)) * D_ + (lane >> 4) * 8;
    #pragma unroll
    for (int kk = 0; kk < 16; ++kk) qf[kk] = *(const bf16x8*)(qp + kk * 32);
  }

  f32x4 acc[2][4] = {};                  // PV: [32 n x 64 d] per wave
  const int dc = w * 64;

  // stage K-tile mt: wave w stages rows m = w*8+i; LDS[m][slot] = Tb[m][slot^(m&7)]
  auto STAGE = [&](int mt) {
    #pragma unroll
    for (int i = 0; i < 8; ++i) {
      int m = w * 8 + i;
      const ushort* g = Tb + (size_t)(mt * BK + m) * D_ + ((lane ^ (m & 7)) * 8);
      gld16(g, &KV[m * D_]);
    }
  };

  STAGE(0);

  for (int t = 0; t < N_ / BK; ++t) {
    const int m0 = t * BK;
    __syncthreads();                     // KV(t) staged (drains vmcnt)

    // ---- S = Q * K^T : 16 MFMA
    f32x4 sacc = {};
    #pragma unroll
    for (int kk = 0; kk < 16; ++kk) {
      int m = kc0 + (lane & 15);
      int slot = kk * 4 + (lane >> 4);
      bf16x8 bfr = *(const bf16x8*)&KV[m * D_ + ((slot ^ (m & 7)) << 3)];
      sacc = __builtin_amdgcn_mfma_f32_16x16x32_bf16(qf[kk], bfr, sacc, 0, 0, 0);
    }

    // ---- epilogue: tanh -> Pl[t&1]
    {
      ushort* P = Pl[t & 1];
      int col = kc0 + (lane & 15);
      #pragma unroll
      for (int j = 0; j < 4; ++j) {
        int row = rq0 + (lane >> 4) * 4 + j;
        float e = __builtin_amdgcn_exp2f(sacc[j] * 2.885390082f);  // e^(2s)
        float tn = 1.0f - 2.0f * __builtin_amdgcn_rcpf(e + 1.0f);
        P[row * BK + (col ^ ((row & 7) << 3))] = (ushort)f2bs(tn);
      }
    }
    __syncthreads();                     // Pl visible; KV consumed

    if (t < N_ / BK - 1) STAGE(t + 1);   // async, overlaps PV

    // ---- out += P * V : 16 MFMA (V from global/L2)
    const ushort* P = Pl[t & 1];
    #pragma unroll
    for (int ks = 0; ks < 2; ++ks) {
      bf16x8 pa[2], vb[4];
      #pragma unroll
      for (int bj = 0; bj < 4; ++bj) {
        const ushort* vp = Vt + (size_t)(dc + bj * 16 + (lane & 15)) * N_
                         + m0 + ks * 32 + (lane >> 4) * 8;
        vb[bj] = *(const bf16x8*)vp;
      }
      #pragma unroll
      for (int ai = 0; ai < 2; ++ai) {
        int row = ai * 16 + (lane & 15);
        int slot = ks * 4 + (lane >> 4);
        pa[ai] = *(const bf16x8*)&P[row * BK + ((slot ^ (row & 7)) << 3)];
      }
      #pragma unroll
      for (int ai = 0; ai < 2; ++ai)
        #pragma unroll
        for (int bj = 0; bj < 4; ++bj)
          acc[ai][bj] = __builtin_amdgcn_mfma_f32_16x16x32_bf16(pa[ai], vb[bj], acc[ai][bj], 0, 0, 0);
    }
  }

  // ---- write out [32 x 512] fp32
  {
    float* op = out + (size_t)b * N_ * D_;
    #pragma unroll
    for (int ai = 0; ai < 2; ++ai)
      #pragma unroll
      for (int j = 0; j < 4; ++j) {
        int row = q0 + ai * 16 + (lane >> 4) * 4 + j;
        #pragma unroll
        for (int bj = 0; bj < 4; ++bj)
          op[(size_t)row * D_ + dc + bj * 16 + (lane & 15)] = acc[ai][bj][j];
      }
  }
}

extern "C" void kernel_launch(void* const* d_in, const int* in_sizes, int n_in,
                              void* d_out, int out_size, void* d_ws, size_t ws_size,
                              hipStream_t stream) {
  const float* tgt = (const float*)d_in[0];
  float* outp = (float*)d_out;

  float*  rn   = (float*)d_ws;                                    // 128 KB
  ushort* Tbf  = (ushort*)((char*)d_ws + (1 << 17));              // 32 MB
  ushort* Ttbf = Tbf + (size_t)B_ * N_ * D_;                      // 32 MB

  rnorm_kernel<<<dim3((B_ * N_) / 4), dim3(256), 0, stream>>>(tgt, rn);
  prep_kernel<<<dim3(B_ * 64 * 8), dim3(256), 0, stream>>>(tgt, rn, Tbf, Ttbf);
  fused_kernel<<<dim3(B_ * (N_ / BM)), dim3(NTH), 0, stream>>>(Tbf, Ttbf, outp);
}

// Round 4
// 362.142 us; speedup vs baseline: 4.1694x; 4.1694x over previous
//
#include <hip/hip_runtime.h>
#include <hip/hip_bf16.h>

#define B_ 8
#define N_ 4096
#define D_ 512
#define BM 64
#define BK 64
#define NTH 512
#define NT (N_ / BK)

typedef __attribute__((ext_vector_type(8))) short bf16x8;
typedef __attribute__((ext_vector_type(4))) float f32x4;
typedef __attribute__((ext_vector_type(16))) float f32x16;

__device__ __forceinline__ short f2bs(float x) {
  union { __hip_bfloat16 h; short s; } u;
  u.h = __float2bfloat16(x);
  return u.s;
}

__device__ __forceinline__ void gld16(const void* g, void* l) {
  __builtin_amdgcn_global_load_lds((const __attribute__((address_space(1))) void*)g,
                                   (__attribute__((address_space(3))) void*)l, 16, 0, 0);
}

// ---------------- kernel 1: rn[b*N+n] = 1/||tgt[b,n,:]|| ----------------
__global__ void __launch_bounds__(256) rnorm_kernel(const float* __restrict__ tgt,
                                                    float* __restrict__ rn) {
  int row  = blockIdx.x * 4 + (threadIdx.x >> 6);
  int lane = threadIdx.x & 63;
  const float* p = tgt + (size_t)row * D_ + lane * 8;
  float4 a = *(const float4*)p;
  float4 b = *(const float4*)(p + 4);
  float s = a.x*a.x + a.y*a.y + a.z*a.z + a.w*a.w
          + b.x*b.x + b.y*b.y + b.z*b.z + b.w*b.w;
  #pragma unroll
  for (int m = 32; m >= 1; m >>= 1) s += __shfl_xor(s, m, 64);
  if (lane == 0) rn[row] = rsqrtf(s);
}

// ---------------- kernel 2: prep granule-8 layouts ----------------
// Tbf2[b][d>>3][n][d&7] = bf16( tgt[b][n][d] * rn[b][n] )   (normalized)
// Vt2 [b][n>>3][d][n&7] = bf16( tgt[b][n][d] )              (raw)
__global__ void __launch_bounds__(256) prep_kernel(const float* __restrict__ tgt,
                                                   const float* __restrict__ rn,
                                                   ushort* __restrict__ Tbf2,
                                                   ushort* __restrict__ Vt2) {
  __shared__ ushort L[64][72];                  // raw bf16 tile, padded
  const int id = blockIdx.x;                    // 8b x 64nt x 8dt
  const int b = id >> 9, nt = (id >> 3) & 63, dt = id & 7;
  const int n0 = nt * 64, d0 = dt * 64;
  const int t = threadIdx.x;
  const float* Tg  = tgt + ((size_t)b * N_ + n0) * D_ + d0;
  const float* rnb = rn + b * N_ + n0;
  ushort* T2 = Tbf2 + (size_t)b * N_ * D_;
  ushort* V2 = Vt2  + (size_t)b * N_ * D_;

  const int r = t >> 3, g = t & 7;              // row-half, d-granule
  #pragma unroll
  for (int p = 0; p < 2; ++p) {
    int row = p * 32 + r;
    const float* src = Tg + (size_t)row * D_ + g * 8;
    float4 f0 = *(const float4*)src;
    float4 f1 = *(const float4*)(src + 4);
    float sc = rnb[row];
    bf16x8 nv;
    nv[0]=f2bs(f0.x*sc); nv[1]=f2bs(f0.y*sc); nv[2]=f2bs(f0.z*sc); nv[3]=f2bs(f0.w*sc);
    nv[4]=f2bs(f1.x*sc); nv[5]=f2bs(f1.y*sc); nv[6]=f2bs(f1.z*sc); nv[7]=f2bs(f1.w*sc);
    *(bf16x8*)(T2 + ((size_t)(d0/8 + g) * N_ + n0 + row) * 8) = nv;
    bf16x8 rv;
    rv[0]=f2bs(f0.x); rv[1]=f2bs(f0.y); rv[2]=f2bs(f0.z); rv[3]=f2bs(f0.w);
    rv[4]=f2bs(f1.x); rv[5]=f2bs(f1.y); rv[6]=f2bs(f1.z); rv[7]=f2bs(f1.w);
    #pragma unroll
    for (int e = 0; e < 8; ++e) L[row][g*8 + e] = (ushort)rv[e];
  }
  __syncthreads();
  // transpose -> Vt2: task (ng, dd): 16B = L[ng*8 + j][dd], j=0..7
  #pragma unroll
  for (int p = 0; p < 2; ++p) {
    int task = p * 256 + t;
    int ng = task >> 6, dd = task & 63;
    bf16x8 v;
    #pragma unroll
    for (int j = 0; j < 8; ++j) v[j] = (short)L[ng*8 + j][dd];
    *(bf16x8*)(V2 + ((size_t)(n0/8 + ng) * D_ + d0 + dd) * 8) = v;
  }
}

// ---------------- kernel 3: fused  out = tanh(Xn Xn^T) * tgt ----------------
// BM=64 q-rows/block, 8 waves, BK=64 m-tiles.
// S: 16x16x32, Q in regs, waves 4qG x 2mG. PV: 32x32x16, waves 2qG x 4dG.
// All LDS ops contiguous (granule-8 layouts). 2 __syncthreads per tile;
// KV(t+1) staged during PV(t), VT(t+1) staged during S(t+1).
__global__ void __launch_bounds__(NTH, 2) fused_kernel(const ushort* __restrict__ Tbf2,
                                                       const ushort* __restrict__ Vt2,
                                                       float* __restrict__ out) {
  __shared__ __align__(16) ushort KV[BK * D_];   // [dgran 64][m 64][8]  64 KB
  __shared__ __align__(16) ushort VT[BK * D_];   // [mblk 8][d 512][8]   64 KB
  __shared__ __align__(16) ushort Pl[BM * BK];   // [mgran 8][q 64][8]    8 KB

  const int id = blockIdx.x;             // 512 blocks
  const int b  = id & 7;                 // batch -> XCD round-robin
  const int q0 = (id >> 3) * BM;

  const int tid  = threadIdx.x;
  const int lane = tid & 63;
  const int w    = tid >> 6;

  const ushort* Tb2 = Tbf2 + (size_t)b * N_ * D_;  // [d/8][n][8] normalized
  const ushort* Vb2 = Vt2  + (size_t)b * N_ * D_;  // [n/8][d][8] raw

  // ---- S mapping: wave -> q rows [qG*16,+16), m cols [mG*32,+32)
  const int qG = w >> 1;
  const int mG = w & 1;

  // Q fragments (normalized): 16 rows x 512 d = 64 VGPR
  bf16x8 qf[16];
  {
    const int row = q0 + qG * 16 + (lane & 15);
    #pragma unroll
    for (int kk = 0; kk < 16; ++kk) {
      int g = kk * 4 + (lane >> 4);
      qf[kk] = *(const bf16x8*)(Tb2 + ((size_t)g * N_ + row) * 8);
    }
  }

  // ---- PV mapping: wave -> q rows [qG2*32,+32), d cols [dG*128,+128)
  const int qG2 = w >> 2;
  const int dG  = w & 3;
  f32x16 acc[4] = {};                    // [32q x 128d] per wave

  // stage K-tile: KV[g][m][e] <- Tb2[g][m0+m][e] ; 64 chunks of 1KB, wave w: g = w*8+i
  auto STAGE_KV = [&](int mt) {
    #pragma unroll
    for (int i = 0; i < 8; ++i) {
      int g = w * 8 + i;
      gld16(Tb2 + ((size_t)g * N_ + mt * BK) * 8 + lane * 8, &KV[g * 512]);
    }
  };
  // stage V-tile: VT[mb][d][e] <- Vb2[m0/8+mb][d][e] ; 8 chunks of 8KB, wave w: mb = w
  auto STAGE_VT = [&](int mt) {
    #pragma unroll
    for (int i = 0; i < 8; ++i) {
      gld16(Vb2 + ((size_t)(mt * 8 + w) * D_) * 8 + i * 512 + lane * 8,
            &VT[w * 4096 + i * 512]);
    }
  };

  STAGE_KV(0);
  STAGE_VT(0);
  __syncthreads();

  for (int t = 0; t < NT; ++t) {
    // ---- S = Qn * Kn^T : 32 MFMA-16x16 per wave (KV(t) valid; VT(t) landing)
    f32x4 sacc[2] = {};
    #pragma unroll
    for (int kk = 0; kk < 16; ++kk) {
      int g = kk * 4 + (lane >> 4);
      #pragma unroll
      for (int f = 0; f < 2; ++f) {
        int m = mG * 32 + f * 16 + (lane & 15);
        bf16x8 bfr = *(const bf16x8*)&KV[g * 512 + m * 8];
        sacc[f] = __builtin_amdgcn_mfma_f32_16x16x32_bf16(qf[kk], bfr, sacc[f], 0, 0, 0);
      }
    }
    // tanh -> Pl[mgran][q][e]
    #pragma unroll
    for (int f = 0; f < 2; ++f) {
      int m = mG * 32 + f * 16 + (lane & 15);
      #pragma unroll
      for (int j = 0; j < 4; ++j) {
        int q = qG * 16 + (lane >> 4) * 4 + j;
        float e = __builtin_amdgcn_exp2f(sacc[f][j] * 2.885390082f);  // e^(2s)
        float tn = 1.0f - 2.0f * __builtin_amdgcn_rcpf(e + 1.0f);
        Pl[(m >> 3) * 512 + q * 8 + (m & 7)] = (ushort)f2bs(tn);
      }
    }
    __syncthreads();              // P visible; VT(t) drained; KV buffer free

    if (t < NT - 1) STAGE_KV(t + 1);     // async, lands during PV

    // ---- out += P * V : 16 MFMA-32x32 per wave
    #pragma unroll
    for (int ks = 0; ks < 4; ++ks) {
      int mh = ks * 2 + (lane >> 5);
      bf16x8 pa = *(const bf16x8*)&Pl[mh * 512 + (qG2 * 32 + (lane & 31)) * 8];
      #pragma unroll
      for (int c = 0; c < 4; ++c) {
        int d = dG * 128 + c * 32 + (lane & 31);
        bf16x8 vb = *(const bf16x8*)&VT[mh * 4096 + d * 8];
        acc[c] = __builtin_amdgcn_mfma_f32_32x32x16_bf16(pa, vb, acc[c], 0, 0, 0);
      }
    }
    __syncthreads();              // KV(t+1) drained; VT buffer free

    if (t < NT - 1) STAGE_VT(t + 1);     // async, lands during next S
  }

  // ---- write out [64 x 512] fp32; C/D 32x32: row=(reg&3)+8*(reg>>2)+4*(lane>>5)
  {
    float* op = out + (size_t)b * N_ * D_ + (size_t)q0 * D_;
    #pragma unroll
    for (int c = 0; c < 4; ++c) {
      int d = dG * 128 + c * 32 + (lane & 31);
      #pragma unroll
      for (int reg = 0; reg < 16; ++reg) {
        int row = qG2 * 32 + (reg & 3) + 8 * (reg >> 2) + 4 * (lane >> 5);
        op[(size_t)row * D_ + d] = acc[c][reg];
      }
    }
  }
}

extern "C" void kernel_launch(void* const* d_in, const int* in_sizes, int n_in,
                              void* d_out, int out_size, void* d_ws, size_t ws_size,
                              hipStream_t stream) {
  const float* tgt = (const float*)d_in[0];
  float* outp = (float*)d_out;

  float*  rn   = (float*)d_ws;                                    // 128 KB
  ushort* Tbf2 = (ushort*)((char*)d_ws + (1 << 17));              // 32 MB
  ushort* Vt2  = Tbf2 + (size_t)B_ * N_ * D_;                     // 32 MB

  rnorm_kernel<<<dim3((B_ * N_) / 4), dim3(256), 0, stream>>>(tgt, rn);
  prep_kernel<<<dim3(B_ * 64 * 8), dim3(256), 0, stream>>>(tgt, rn, Tbf2, Vt2);
  fused_kernel<<<dim3(B_ * (N_ / BM)), dim3(NTH), 0, stream>>>(Tbf2, Vt2, outp);
}